// Round 4
// baseline (113.586 us; speedup 1.0000x reference)
//
#include <hip/hip_runtime.h>

// Problem constants (fixed by the reference):
//   x: [B=2, D=32, 256,256,16] f32 ; N = 256*256*16 = 2^20 per row
//   mean over D, top-K=500 per row, out[b,n] = selected ? 10*mean : 0
#define B 2
#define D 32
#define NLOG 20
#define N (1 << NLOG)
#define N4 (N / 4)            // 262144 float4 per row
#define KSEL 500
#define CAP 32768             // candidate capacity per row (expect ~3K)
#define TIE_CAP 2048
#define HBINS 2048
#define NREP 16               // global histogram replicas

typedef float f32x4 __attribute__((ext_vector_type(4)));

// workspace layout (bytes)
#define OFF_MEAN 0u
#define OFF_HIST 8388608u                     // B*NREP*2048*4 = 262144
#define OFF_CKEY (OFF_HIST + 262144u)         // B*CAP*4 = 262144
#define OFF_CIDX (OFF_CKEY + 262144u)         // 262144
#define OFF_CCNT (OFF_CIDX + 262144u)         // 64 (padded)
#define OFF_META (OFF_CCNT + 64u)             // B*8*4 = 64

// order-preserving f32 -> u32 key (ascending); exact bijection
__device__ __forceinline__ unsigned xkey(float f) {
    unsigned u = __float_as_uint(f);
    return (u & 0x80000000u) ? ~u : (u | 0x80000000u);
}
__device__ __forceinline__ float xkey_inv(unsigned key) {
    unsigned u = (key & 0x80000000u) ? (key & 0x7FFFFFFFu) : ~key;
    return __uint_as_float(u);
}

// ---------------------------------------------------------------------------
// Kernel Z: zero hist replicas + ccnt. grid = 256 x 256.
// ---------------------------------------------------------------------------
__global__ __launch_bounds__(256) void zero_kernel(
    unsigned* __restrict__ hist, unsigned* __restrict__ ccnt)
{
    const int i = blockIdx.x * 256 + threadIdx.x;
    hist[i] = 0;                       // exactly B*NREP*HBINS = 65536 threads
    if (i < 16) ccnt[i] = 0;
}

// ---------------------------------------------------------------------------
// Kernel A: PURE streaming mean over D (sequential accumulation order) +
// zero-fill output. No LDS, no atomics, no syncthreads.
// grid = B*N4/256 x 256; each thread owns one float4 (4 n's).
// ---------------------------------------------------------------------------
__global__ __launch_bounds__(256) void mean_kernel(
    const f32x4* __restrict__ x, f32x4* __restrict__ mean,
    f32x4* __restrict__ out)
{
    const int g  = blockIdx.x * 256 + threadIdx.x;   // [0, B*N4)
    const int b  = g >> 18;                          // N4 = 2^18
    const int n4 = g & (N4 - 1);
    const f32x4* xb = x + ((long)b << 23);           // b * D * N4

    f32x4 acc = __builtin_nontemporal_load(xb + n4);
#pragma unroll
    for (int d = 1; d < D; ++d) {
        f32x4 v = __builtin_nontemporal_load(xb + ((long)d << 18) + n4);
        acc.x += v.x; acc.y += v.y; acc.z += v.z; acc.w += v.w;
    }
    acc.x *= 0.03125f; acc.y *= 0.03125f; acc.z *= 0.03125f; acc.w *= 0.03125f;
    mean[g] = acc;                                   // cached: re-read soon
    f32x4 z = {0.f, 0.f, 0.f, 0.f};
    __builtin_nontemporal_store(z, out + g);         // fixed up by scatter
}

// ---------------------------------------------------------------------------
// Kernel H: histogram of top-11 key bits over mean[] (L2/L3-resident).
// grid = B*N4/256 x 256.
// ---------------------------------------------------------------------------
__global__ __launch_bounds__(256) void hist_kernel(
    const f32x4* __restrict__ mean, unsigned* __restrict__ hist)
{
    __shared__ unsigned lh[HBINS];
    const int tid = threadIdx.x;
    for (int i = tid; i < HBINS; i += 256) lh[i] = 0;
    __syncthreads();

    const int g = blockIdx.x * 256 + tid;
    const int b = g >> 18;
    const f32x4 m = mean[g];
    atomicAdd(&lh[xkey(m.x) >> 21], 1u);
    atomicAdd(&lh[xkey(m.y) >> 21], 1u);
    atomicAdd(&lh[xkey(m.z) >> 21], 1u);
    atomicAdd(&lh[xkey(m.w) >> 21], 1u);
    __syncthreads();

    unsigned* gh = hist + ((b * NREP) + (blockIdx.x & (NREP - 1))) * HBINS;
    for (int i = tid; i < HBINS; i += 256)
        if (lh[i]) atomicAdd(&gh[i], lh[i]);
}

// ---------------------------------------------------------------------------
// Kernel B: sum replicas, find bin containing the K-th largest. grid=B x 256.
// ---------------------------------------------------------------------------
__global__ __launch_bounds__(256) void select_bin_kernel(
    const unsigned* __restrict__ hist, unsigned* __restrict__ meta)
{
    __shared__ unsigned h[HBINS];
    __shared__ unsigned ssum[256];
    const int b = blockIdx.x, t = threadIdx.x;
    const unsigned* gh = hist + b * NREP * HBINS;
    for (int i = t; i < HBINS; i += 256) {
        unsigned s = 0;
        for (int r = 0; r < NREP; ++r) s += gh[r * HBINS + i];
        h[i] = s;
    }
    __syncthreads();
    unsigned s = 0;
    for (int j = 0; j < 8; ++j) s += h[t * 8 + j];
    ssum[t] = s;
    __syncthreads();
    unsigned suf = 0;
    for (int u = t + 1; u < 256; ++u) suf += ssum[u];
    unsigned cum = suf;                       // count of elements in bins above
    for (int j = 7; j >= 0; --j) {
        const int bin = t * 8 + j;
        const unsigned c = h[bin];
        if (cum < KSEL && cum + c >= KSEL) meta[b * 8 + 0] = (unsigned)bin;
        cum += c;
    }
}

// ---------------------------------------------------------------------------
// Kernel C: collect candidates (bin >= boundary bin), block-aggregated
// reservation (one global atomic per block). grid = B*N4/256 x 256.
// ---------------------------------------------------------------------------
__global__ __launch_bounds__(256) void collect_kernel(
    const f32x4* __restrict__ mean, const unsigned* __restrict__ meta,
    unsigned* __restrict__ ckey, unsigned* __restrict__ cidx,
    unsigned* __restrict__ ccnt)
{
    __shared__ unsigned lcnt;
    __shared__ unsigned lbase;
    __shared__ unsigned lkey[1024];
    __shared__ unsigned lidx[1024];
    const int t = threadIdx.x;
    if (t == 0) lcnt = 0;
    __syncthreads();

    const int g  = blockIdx.x * 256 + t;
    const int b  = g >> 18;
    const int n4 = g & (N4 - 1);
    const unsigned bin1 = meta[b * 8 + 0];
    const f32x4 m = mean[g];
    const float mv[4] = {m.x, m.y, m.z, m.w};
#pragma unroll
    for (int j = 0; j < 4; ++j) {
        const unsigned key = xkey(mv[j]);
        if ((key >> 21) >= bin1) {
            const unsigned p = atomicAdd(&lcnt, 1u);   // LDS atomic, rare
            lkey[p] = key;
            lidx[p] = (unsigned)(n4 * 4 + j);
        }
    }
    __syncthreads();
    if (t == 0) lbase = (lcnt > 0) ? atomicAdd(&ccnt[b], lcnt) : 0u;
    __syncthreads();
    const unsigned cnt = lcnt, base = lbase;
    for (unsigned j = t; j < cnt; j += 256) {
        const unsigned p = base + j;
        if (p < CAP) {
            ckey[b * CAP + p] = lkey[j];
            cidx[b * CAP + p] = lidx[j];
        }
    }
}

// ---------------------------------------------------------------------------
// Kernel D: exact K-th key via 3-pass radix select over candidates, then
// scatter the selected outputs directly (values recovered bit-exactly from
// keys) with jax tie-break (ascending index). grid = B x 1024.
// ---------------------------------------------------------------------------
__global__ __launch_bounds__(1024) void radix_select_scatter_kernel(
    const unsigned* __restrict__ ckey, const unsigned* __restrict__ cidx,
    const unsigned* __restrict__ ccnt, float* __restrict__ out)
{
    __shared__ unsigned hist[HBINS];
    __shared__ unsigned ssum[256];
    __shared__ unsigned sfound[2];
    __shared__ unsigned tcnt;
    __shared__ unsigned tlist[TIE_CAP];

    const int b = blockIdx.x, t = threadIdx.x;
    unsigned M = ccnt[b]; if (M > CAP) M = CAP;
    const unsigned* keys = ckey + b * CAP;
    const unsigned* idxs = cidx + b * CAP;
    float* outb = out + (long)b * N;

    unsigned r = KSEL;       // rank sought within current prefix group
    unsigned prefix = 0;

    for (int pass = 0; pass < 3; ++pass) {
        const int nb = (pass == 2) ? 1024 : 2048;
        for (int i = t; i < nb; i += 1024) hist[i] = 0;
        __syncthreads();
        for (unsigned i = t; i < M; i += 1024) {
            const unsigned key = keys[i];
            const bool match = (pass == 0) ? true
                             : (pass == 1) ? ((key >> 21) == (prefix >> 21))
                                           : ((key >> 10) == (prefix >> 10));
            if (match) {
                const unsigned dg = (pass == 0) ? (key >> 21)
                                  : (pass == 1) ? ((key >> 10) & 0x7FFu)
                                                : (key & 0x3FFu);
                atomicAdd(&hist[dg], 1u);
            }
        }
        __syncthreads();
        const int chunk = nb / 256;
        if (t < 256) {
            unsigned s = 0;
            for (int j = 0; j < chunk; ++j) s += hist[t * chunk + j];
            ssum[t] = s;
        }
        __syncthreads();
        if (t < 256) {
            unsigned suf = 0;
            for (int u = t + 1; u < 256; ++u) suf += ssum[u];
            unsigned cum = suf;
            for (int j = chunk - 1; j >= 0; --j) {
                const int g2 = t * chunk + j;
                const unsigned c = hist[g2];
                if (cum < r && cum + c >= r) { sfound[0] = (unsigned)g2; sfound[1] = cum; }
                cum += c;
            }
        }
        __syncthreads();
        const unsigned fd = sfound[0], ca = sfound[1];
        r -= ca;
        prefix |= fd << ((pass == 0) ? 21 : (pass == 1) ? 10 : 0);
        __syncthreads();
    }
    // prefix = T (key of the K-th largest); r = # of ties to take (asc index)
    const unsigned T = prefix;
    const float tv = xkey_inv(T);

    if (t == 0) tcnt = 0;
    __syncthreads();
    for (unsigned i = t; i < M; i += 1024) {
        const unsigned key = keys[i];
        if (key > T) {
            outb[idxs[i]] = 10.0f * xkey_inv(key);   // strictly above: selected
        } else if (key == T) {
            const unsigned p = atomicAdd(&tcnt, 1u);
            if (p < TIE_CAP) tlist[p] = i;
        }
    }
    __syncthreads();
    unsigned E = tcnt; if (E > TIE_CAP) E = TIE_CAP;
    for (unsigned j = t; j < E; j += 1024) {
        const unsigned idxj = idxs[tlist[j]];
        unsigned rank = 0;
        for (unsigned k2 = 0; k2 < E; ++k2) rank += (idxs[tlist[k2]] < idxj) ? 1u : 0u;
        if (rank < r) outb[idxj] = 10.0f * tv;
    }
}

extern "C" void kernel_launch(void* const* d_in, const int* in_sizes, int n_in,
                              void* d_out, int out_size, void* d_ws, size_t ws_size,
                              hipStream_t stream)
{
    const f32x4* x = (const f32x4*)d_in[0];
    char* wsb = (char*)d_ws;
    f32x4*    mean = (f32x4*)(wsb + OFF_MEAN);
    unsigned* hist = (unsigned*)(wsb + OFF_HIST);
    unsigned* ckey = (unsigned*)(wsb + OFF_CKEY);
    unsigned* cidx = (unsigned*)(wsb + OFF_CIDX);
    unsigned* ccnt = (unsigned*)(wsb + OFF_CCNT);
    unsigned* meta = (unsigned*)(wsb + OFF_META);

    const int grid = B * N4 / 256;   // 2048
    zero_kernel<<<256, 256, 0, stream>>>(hist, ccnt);
    mean_kernel<<<grid, 256, 0, stream>>>(x, mean, (f32x4*)d_out);
    hist_kernel<<<grid, 256, 0, stream>>>(mean, hist);
    select_bin_kernel<<<B, 256, 0, stream>>>(hist, meta);
    collect_kernel<<<grid, 256, 0, stream>>>(mean, meta, ckey, cidx, ccnt);
    radix_select_scatter_kernel<<<B, 1024, 0, stream>>>(ckey, cidx, ccnt, (float*)d_out);
}

// Round 5
// 99.780 us; speedup vs baseline: 1.1384x; 1.1384x over previous
//
#include <hip/hip_runtime.h>

// Problem constants (fixed by the reference):
//   x: [B=2, D=32, 256,256,16] f32 ; N = 256*256*16 = 2^20 per row
//   mean over D, top-K=500 per row, out[b,n] = selected ? 10*mean : 0
#define B 2
#define D 32
#define NLOG 20
#define N (1 << NLOG)
#define N4 (N / 4)            // 262144 float4 per row
#define KSEL 500
#define CAP 32768             // candidate capacity per row (expect ~3K)
#define TIE_CAP 2048
#define HBINS 2048
#define NREP 16               // global histogram replicas

typedef float f32x4 __attribute__((ext_vector_type(4)));

// workspace layout (bytes)
#define OFF_MEAN 0u
#define OFF_HIST 8388608u                     // B*NREP*2048*4 = 262144
#define OFF_CKEY (OFF_HIST + 262144u)         // B*CAP*4 = 262144
#define OFF_CIDX (OFF_CKEY + 262144u)         // 262144
#define OFF_CCNT (OFF_CIDX + 262144u)         // 64 (padded)
#define OFF_META (OFF_CCNT + 64u)             // B*8*4 = 64

// order-preserving f32 -> u32 key (ascending); exact bijection
__device__ __forceinline__ unsigned xkey(float f) {
    unsigned u = __float_as_uint(f);
    return (u & 0x80000000u) ? ~u : (u | 0x80000000u);
}
__device__ __forceinline__ float xkey_inv(unsigned key) {
    unsigned u = (key & 0x80000000u) ? (key & 0x7FFFFFFFu) : ~key;
    return __uint_as_float(u);
}

// ---------------------------------------------------------------------------
// Kernel Z: zero hist replicas + ccnt. grid = 256 x 256.
// ---------------------------------------------------------------------------
__global__ __launch_bounds__(256) void zero_kernel(
    unsigned* __restrict__ hist, unsigned* __restrict__ ccnt)
{
    const int i = blockIdx.x * 256 + threadIdx.x;
    hist[i] = 0;                       // exactly B*NREP*HBINS = 65536 threads
    if (i < 16) ccnt[i] = 0;
}

// ---------------------------------------------------------------------------
// Kernel A: fused mean over D + histogram + out zero-fill (R3 structure),
// restructured: 1024 blocks x 256 threads x 2 float4/thread -> each block
// reads 8 KB contiguous per d-plane (halves concurrent DRAM streams, doubles
// burst length). Plain loads (no NT — NT regressed in R4). Per-element
// accumulation order is still strictly sequential in d (bit-exact vs numpy).
// ---------------------------------------------------------------------------
__global__ __launch_bounds__(256) void mean_hist_kernel(
    const f32x4* __restrict__ x, f32x4* __restrict__ mean,
    unsigned* __restrict__ hist, f32x4* __restrict__ out)
{
    __shared__ unsigned lh[HBINS];
    const int tid = threadIdx.x;
    for (int i = tid; i < HBINS; i += 256) lh[i] = 0;
    __syncthreads();

    const int g0 = blockIdx.x * 512 + tid;     // first float4 index
    const int g1 = g0 + 256;                   // second float4 index
    const int b  = g0 >> 18;                   // 512 divides 2^18 -> uniform
    const int n0 = g0 & (N4 - 1);
    const int n1 = g1 & (N4 - 1);
    const f32x4* xb = x + ((long)b << 23);     // b * D * N4

    f32x4 a0 = xb[n0];
    f32x4 a1 = xb[n1];
#pragma unroll
    for (int d = 1; d < D; ++d) {
        const f32x4* p = xb + ((long)d << 18);
        f32x4 v0 = p[n0];
        f32x4 v1 = p[n1];
        a0.x += v0.x; a0.y += v0.y; a0.z += v0.z; a0.w += v0.w;
        a1.x += v1.x; a1.y += v1.y; a1.z += v1.z; a1.w += v1.w;
    }
    a0.x *= 0.03125f; a0.y *= 0.03125f; a0.z *= 0.03125f; a0.w *= 0.03125f;
    a1.x *= 0.03125f; a1.y *= 0.03125f; a1.z *= 0.03125f; a1.w *= 0.03125f;
    mean[g0] = a0;                             // cached: re-read by collect
    mean[g1] = a1;
    f32x4 z = {0.f, 0.f, 0.f, 0.f};
    __builtin_nontemporal_store(z, out + g0);  // fixed up by scatter
    __builtin_nontemporal_store(z, out + g1);

    atomicAdd(&lh[xkey(a0.x) >> 21], 1u);
    atomicAdd(&lh[xkey(a0.y) >> 21], 1u);
    atomicAdd(&lh[xkey(a0.z) >> 21], 1u);
    atomicAdd(&lh[xkey(a0.w) >> 21], 1u);
    atomicAdd(&lh[xkey(a1.x) >> 21], 1u);
    atomicAdd(&lh[xkey(a1.y) >> 21], 1u);
    atomicAdd(&lh[xkey(a1.z) >> 21], 1u);
    atomicAdd(&lh[xkey(a1.w) >> 21], 1u);
    __syncthreads();

    // flush to one of NREP replicas -> same-address chains /16
    unsigned* gh = hist + ((b * NREP) + (blockIdx.x & (NREP - 1))) * HBINS;
    for (int i = tid; i < HBINS; i += 256)
        if (lh[i]) atomicAdd(&gh[i], lh[i]);
}

// ---------------------------------------------------------------------------
// Kernel B: sum replicas, find bin containing the K-th largest. grid=B x 256.
// ---------------------------------------------------------------------------
__global__ __launch_bounds__(256) void select_bin_kernel(
    const unsigned* __restrict__ hist, unsigned* __restrict__ meta)
{
    __shared__ unsigned h[HBINS];
    __shared__ unsigned ssum[256];
    const int b = blockIdx.x, t = threadIdx.x;
    const unsigned* gh = hist + b * NREP * HBINS;
    for (int i = t; i < HBINS; i += 256) {
        unsigned s = 0;
        for (int r = 0; r < NREP; ++r) s += gh[r * HBINS + i];
        h[i] = s;
    }
    __syncthreads();
    unsigned s = 0;
    for (int j = 0; j < 8; ++j) s += h[t * 8 + j];
    ssum[t] = s;
    __syncthreads();
    unsigned suf = 0;
    for (int u = t + 1; u < 256; ++u) suf += ssum[u];
    unsigned cum = suf;                       // count of elements in bins above
    for (int j = 7; j >= 0; --j) {
        const int bin = t * 8 + j;
        const unsigned c = h[bin];
        if (cum < KSEL && cum + c >= KSEL) meta[b * 8 + 0] = (unsigned)bin;
        cum += c;
    }
}

// ---------------------------------------------------------------------------
// Kernel C: collect candidates (bin >= boundary bin), block-aggregated
// reservation (one global atomic per block). grid = B*N4/256 x 256.
// ---------------------------------------------------------------------------
__global__ __launch_bounds__(256) void collect_kernel(
    const f32x4* __restrict__ mean, const unsigned* __restrict__ meta,
    unsigned* __restrict__ ckey, unsigned* __restrict__ cidx,
    unsigned* __restrict__ ccnt)
{
    __shared__ unsigned lcnt;
    __shared__ unsigned lbase;
    __shared__ unsigned lkey[1024];
    __shared__ unsigned lidx[1024];
    const int t = threadIdx.x;
    if (t == 0) lcnt = 0;
    __syncthreads();

    const int g  = blockIdx.x * 256 + t;
    const int b  = g >> 18;
    const int n4 = g & (N4 - 1);
    const unsigned bin1 = meta[b * 8 + 0];
    const f32x4 m = mean[g];
    const float mv[4] = {m.x, m.y, m.z, m.w};
#pragma unroll
    for (int j = 0; j < 4; ++j) {
        const unsigned key = xkey(mv[j]);
        if ((key >> 21) >= bin1) {
            const unsigned p = atomicAdd(&lcnt, 1u);   // LDS atomic, rare
            lkey[p] = key;
            lidx[p] = (unsigned)(n4 * 4 + j);
        }
    }
    __syncthreads();
    if (t == 0) lbase = (lcnt > 0) ? atomicAdd(&ccnt[b], lcnt) : 0u;
    __syncthreads();
    const unsigned cnt = lcnt, base = lbase;
    for (unsigned j = t; j < cnt; j += 256) {
        const unsigned p = base + j;
        if (p < CAP) {
            ckey[b * CAP + p] = lkey[j];
            cidx[b * CAP + p] = lidx[j];
        }
    }
}

// ---------------------------------------------------------------------------
// Kernel D: exact K-th key via 3-pass radix select over candidates, then
// scatter the selected outputs directly (values recovered bit-exactly from
// keys) with jax tie-break (ascending index). grid = B x 1024.
// ---------------------------------------------------------------------------
__global__ __launch_bounds__(1024) void radix_select_scatter_kernel(
    const unsigned* __restrict__ ckey, const unsigned* __restrict__ cidx,
    const unsigned* __restrict__ ccnt, float* __restrict__ out)
{
    __shared__ unsigned hist[HBINS];
    __shared__ unsigned ssum[256];
    __shared__ unsigned sfound[2];
    __shared__ unsigned tcnt;
    __shared__ unsigned tlist[TIE_CAP];

    const int b = blockIdx.x, t = threadIdx.x;
    unsigned M = ccnt[b]; if (M > CAP) M = CAP;
    const unsigned* keys = ckey + b * CAP;
    const unsigned* idxs = cidx + b * CAP;
    float* outb = out + (long)b * N;

    unsigned r = KSEL;       // rank sought within current prefix group
    unsigned prefix = 0;

    for (int pass = 0; pass < 3; ++pass) {
        const int nb = (pass == 2) ? 1024 : 2048;
        for (int i = t; i < nb; i += 1024) hist[i] = 0;
        __syncthreads();
        for (unsigned i = t; i < M; i += 1024) {
            const unsigned key = keys[i];
            const bool match = (pass == 0) ? true
                             : (pass == 1) ? ((key >> 21) == (prefix >> 21))
                                           : ((key >> 10) == (prefix >> 10));
            if (match) {
                const unsigned dg = (pass == 0) ? (key >> 21)
                                  : (pass == 1) ? ((key >> 10) & 0x7FFu)
                                                : (key & 0x3FFu);
                atomicAdd(&hist[dg], 1u);
            }
        }
        __syncthreads();
        const int chunk = nb / 256;
        if (t < 256) {
            unsigned s = 0;
            for (int j = 0; j < chunk; ++j) s += hist[t * chunk + j];
            ssum[t] = s;
        }
        __syncthreads();
        if (t < 256) {
            unsigned suf = 0;
            for (int u = t + 1; u < 256; ++u) suf += ssum[u];
            unsigned cum = suf;
            for (int j = chunk - 1; j >= 0; --j) {
                const int g2 = t * chunk + j;
                const unsigned c = hist[g2];
                if (cum < r && cum + c >= r) { sfound[0] = (unsigned)g2; sfound[1] = cum; }
                cum += c;
            }
        }
        __syncthreads();
        const unsigned fd = sfound[0], ca = sfound[1];
        r -= ca;
        prefix |= fd << ((pass == 0) ? 21 : (pass == 1) ? 10 : 0);
        __syncthreads();
    }
    // prefix = T (key of the K-th largest); r = # of ties to take (asc index)
    const unsigned T = prefix;
    const float tv = xkey_inv(T);

    if (t == 0) tcnt = 0;
    __syncthreads();
    for (unsigned i = t; i < M; i += 1024) {
        const unsigned key = keys[i];
        if (key > T) {
            outb[idxs[i]] = 10.0f * xkey_inv(key);   // strictly above: selected
        } else if (key == T) {
            const unsigned p = atomicAdd(&tcnt, 1u);
            if (p < TIE_CAP) tlist[p] = i;
        }
    }
    __syncthreads();
    unsigned E = tcnt; if (E > TIE_CAP) E = TIE_CAP;
    for (unsigned j = t; j < E; j += 1024) {
        const unsigned idxj = idxs[tlist[j]];
        unsigned rank = 0;
        for (unsigned k2 = 0; k2 < E; ++k2) rank += (idxs[tlist[k2]] < idxj) ? 1u : 0u;
        if (rank < r) outb[idxj] = 10.0f * tv;
    }
}

extern "C" void kernel_launch(void* const* d_in, const int* in_sizes, int n_in,
                              void* d_out, int out_size, void* d_ws, size_t ws_size,
                              hipStream_t stream)
{
    const f32x4* x = (const f32x4*)d_in[0];
    char* wsb = (char*)d_ws;
    f32x4*    mean = (f32x4*)(wsb + OFF_MEAN);
    unsigned* hist = (unsigned*)(wsb + OFF_HIST);
    unsigned* ckey = (unsigned*)(wsb + OFF_CKEY);
    unsigned* cidx = (unsigned*)(wsb + OFF_CIDX);
    unsigned* ccnt = (unsigned*)(wsb + OFF_CCNT);
    unsigned* meta = (unsigned*)(wsb + OFF_META);

    zero_kernel<<<256, 256, 0, stream>>>(hist, ccnt);
    mean_hist_kernel<<<B * N4 / 512, 256, 0, stream>>>(x, mean, hist, (f32x4*)d_out);
    select_bin_kernel<<<B, 256, 0, stream>>>(hist, meta);
    collect_kernel<<<B * N4 / 256, 256, 0, stream>>>(mean, meta, ckey, cidx, ccnt);
    radix_select_scatter_kernel<<<B, 1024, 0, stream>>>(ckey, cidx, ccnt, (float*)d_out);
}

// Round 6
// 95.832 us; speedup vs baseline: 1.1853x; 1.0412x over previous
//
#include <hip/hip_runtime.h>

// Problem constants (fixed by the reference):
//   x: [B=2, D=32, 256,256,16] f32 ; N = 256*256*16 = 2^20 per row
//   mean over D, top-K=500 per row, out[b,n] = selected ? 10*mean : 0
#define B 2
#define D 32
#define NLOG 20
#define N (1 << NLOG)
#define N4 (N / 4)            // 262144 float4 per row
#define KSEL 500
#define CAP 32768             // candidate capacity per row (expect ~3K)
#define TIE_CAP 2048
#define HBINS 2048
#define NREP 16               // global histogram replicas
#define STREAMS 4             // float4 streams per thread in mean kernel

typedef float f32x4 __attribute__((ext_vector_type(4)));

// workspace layout (bytes)
#define OFF_MEAN 0u
#define OFF_HIST 8388608u                     // B*NREP*2048*4 = 262144
#define OFF_CKEY (OFF_HIST + 262144u)         // B*CAP*4 = 262144
#define OFF_CIDX (OFF_CKEY + 262144u)         // 262144
#define OFF_CCNT (OFF_CIDX + 262144u)         // 64 (padded)
#define OFF_META (OFF_CCNT + 64u)             // B*8*4 = 64

// order-preserving f32 -> u32 key (ascending); exact bijection
__device__ __forceinline__ unsigned xkey(float f) {
    unsigned u = __float_as_uint(f);
    return (u & 0x80000000u) ? ~u : (u | 0x80000000u);
}
__device__ __forceinline__ float xkey_inv(unsigned key) {
    unsigned u = (key & 0x80000000u) ? (key & 0x7FFFFFFFu) : ~key;
    return __uint_as_float(u);
}

// ---------------------------------------------------------------------------
// Kernel Z: zero hist replicas + ccnt. grid = 256 x 256.
// ---------------------------------------------------------------------------
__global__ __launch_bounds__(256) void zero_kernel(
    unsigned* __restrict__ hist, unsigned* __restrict__ ccnt)
{
    const int i = blockIdx.x * 256 + threadIdx.x;
    hist[i] = 0;                       // exactly B*NREP*HBINS = 65536 threads
    if (i < 16) ccnt[i] = 0;
}

// ---------------------------------------------------------------------------
// Kernel A: fused mean over D + histogram + out zero-fill.
// 512 blocks x 256 threads x 4 float4/thread: each block reads 16 KB
// contiguous per d-plane. #pragma unroll 4 keeps <=16 loads in flight per
// wave (bounded VGPR — full unroll hoisted too much in R5). Plain loads and
// stores (NT loads regressed in R4; NT stores never isolated — dropped).
// Per-stream accumulation strictly sequential in d (bit-exact vs numpy).
// ---------------------------------------------------------------------------
__global__ __launch_bounds__(256) void mean_hist_kernel(
    const f32x4* __restrict__ x, f32x4* __restrict__ mean,
    unsigned* __restrict__ hist, f32x4* __restrict__ out)
{
    __shared__ unsigned lh[HBINS];
    const int tid = threadIdx.x;
    for (int i = tid; i < HBINS; i += 256) lh[i] = 0;
    __syncthreads();

    const int g0 = blockIdx.x * (256 * STREAMS) + tid;  // first f4 index
    const int b  = g0 >> 18;            // 1024 divides 2^18 -> uniform per blk
    const f32x4* xb = x + ((long)b << 23) + (g0 & (N4 - 1));  // d=0 base

    f32x4 a[STREAMS];
#pragma unroll
    for (int s = 0; s < STREAMS; ++s) a[s] = xb[s * 256];

    const f32x4* p = xb;
#pragma unroll 4
    for (int d = 1; d < D; ++d) {
        p += N4;
#pragma unroll
        for (int s = 0; s < STREAMS; ++s) {
            f32x4 v = p[s * 256];
            a[s].x += v.x; a[s].y += v.y; a[s].z += v.z; a[s].w += v.w;
        }
    }

    const f32x4 z = {0.f, 0.f, 0.f, 0.f};
#pragma unroll
    for (int s = 0; s < STREAMS; ++s) {
        a[s].x *= 0.03125f; a[s].y *= 0.03125f;
        a[s].z *= 0.03125f; a[s].w *= 0.03125f;
        mean[g0 + s * 256] = a[s];
        out[g0 + s * 256]  = z;         // fixed up by scatter
        atomicAdd(&lh[xkey(a[s].x) >> 21], 1u);
        atomicAdd(&lh[xkey(a[s].y) >> 21], 1u);
        atomicAdd(&lh[xkey(a[s].z) >> 21], 1u);
        atomicAdd(&lh[xkey(a[s].w) >> 21], 1u);
    }
    __syncthreads();

    // flush to one of NREP replicas -> same-address chains /16
    unsigned* gh = hist + ((b * NREP) + (blockIdx.x & (NREP - 1))) * HBINS;
    for (int i = tid; i < HBINS; i += 256)
        if (lh[i]) atomicAdd(&gh[i], lh[i]);
}

// ---------------------------------------------------------------------------
// Kernel B: sum replicas, find bin containing the K-th largest. grid=B x 256.
// ---------------------------------------------------------------------------
__global__ __launch_bounds__(256) void select_bin_kernel(
    const unsigned* __restrict__ hist, unsigned* __restrict__ meta)
{
    __shared__ unsigned h[HBINS];
    __shared__ unsigned ssum[256];
    const int b = blockIdx.x, t = threadIdx.x;
    const unsigned* gh = hist + b * NREP * HBINS;
    for (int i = t; i < HBINS; i += 256) {
        unsigned s = 0;
        for (int r = 0; r < NREP; ++r) s += gh[r * HBINS + i];
        h[i] = s;
    }
    __syncthreads();
    unsigned s = 0;
    for (int j = 0; j < 8; ++j) s += h[t * 8 + j];
    ssum[t] = s;
    __syncthreads();
    unsigned suf = 0;
    for (int u = t + 1; u < 256; ++u) suf += ssum[u];
    unsigned cum = suf;                       // count of elements in bins above
    for (int j = 7; j >= 0; --j) {
        const int bin = t * 8 + j;
        const unsigned c = h[bin];
        if (cum < KSEL && cum + c >= KSEL) meta[b * 8 + 0] = (unsigned)bin;
        cum += c;
    }
}

// ---------------------------------------------------------------------------
// Kernel C: collect candidates (bin >= boundary bin), block-aggregated
// reservation (one global atomic per block). grid = B*N4/256 x 256.
// ---------------------------------------------------------------------------
__global__ __launch_bounds__(256) void collect_kernel(
    const f32x4* __restrict__ mean, const unsigned* __restrict__ meta,
    unsigned* __restrict__ ckey, unsigned* __restrict__ cidx,
    unsigned* __restrict__ ccnt)
{
    __shared__ unsigned lcnt;
    __shared__ unsigned lbase;
    __shared__ unsigned lkey[1024];
    __shared__ unsigned lidx[1024];
    const int t = threadIdx.x;
    if (t == 0) lcnt = 0;
    __syncthreads();

    const int g  = blockIdx.x * 256 + t;
    const int b  = g >> 18;
    const int n4 = g & (N4 - 1);
    const unsigned bin1 = meta[b * 8 + 0];
    const f32x4 m = mean[g];
    const float mv[4] = {m.x, m.y, m.z, m.w};
#pragma unroll
    for (int j = 0; j < 4; ++j) {
        const unsigned key = xkey(mv[j]);
        if ((key >> 21) >= bin1) {
            const unsigned p = atomicAdd(&lcnt, 1u);   // LDS atomic, rare
            lkey[p] = key;
            lidx[p] = (unsigned)(n4 * 4 + j);
        }
    }
    __syncthreads();
    if (t == 0) lbase = (lcnt > 0) ? atomicAdd(&ccnt[b], lcnt) : 0u;
    __syncthreads();
    const unsigned cnt = lcnt, base = lbase;
    for (unsigned j = t; j < cnt; j += 256) {
        const unsigned p = base + j;
        if (p < CAP) {
            ckey[b * CAP + p] = lkey[j];
            cidx[b * CAP + p] = lidx[j];
        }
    }
}

// ---------------------------------------------------------------------------
// Kernel D: exact K-th key via 3-pass radix select over candidates, then
// scatter the selected outputs directly (values recovered bit-exactly from
// keys) with jax tie-break (ascending index). grid = B x 1024.
// ---------------------------------------------------------------------------
__global__ __launch_bounds__(1024) void radix_select_scatter_kernel(
    const unsigned* __restrict__ ckey, const unsigned* __restrict__ cidx,
    const unsigned* __restrict__ ccnt, float* __restrict__ out)
{
    __shared__ unsigned hist[HBINS];
    __shared__ unsigned ssum[256];
    __shared__ unsigned sfound[2];
    __shared__ unsigned tcnt;
    __shared__ unsigned tlist[TIE_CAP];

    const int b = blockIdx.x, t = threadIdx.x;
    unsigned M = ccnt[b]; if (M > CAP) M = CAP;
    const unsigned* keys = ckey + b * CAP;
    const unsigned* idxs = cidx + b * CAP;
    float* outb = out + (long)b * N;

    unsigned r = KSEL;       // rank sought within current prefix group
    unsigned prefix = 0;

    for (int pass = 0; pass < 3; ++pass) {
        const int nb = (pass == 2) ? 1024 : 2048;
        for (int i = t; i < nb; i += 1024) hist[i] = 0;
        __syncthreads();
        for (unsigned i = t; i < M; i += 1024) {
            const unsigned key = keys[i];
            const bool match = (pass == 0) ? true
                             : (pass == 1) ? ((key >> 21) == (prefix >> 21))
                                           : ((key >> 10) == (prefix >> 10));
            if (match) {
                const unsigned dg = (pass == 0) ? (key >> 21)
                                  : (pass == 1) ? ((key >> 10) & 0x7FFu)
                                                : (key & 0x3FFu);
                atomicAdd(&hist[dg], 1u);
            }
        }
        __syncthreads();
        const int chunk = nb / 256;
        if (t < 256) {
            unsigned s = 0;
            for (int j = 0; j < chunk; ++j) s += hist[t * chunk + j];
            ssum[t] = s;
        }
        __syncthreads();
        if (t < 256) {
            unsigned suf = 0;
            for (int u = t + 1; u < 256; ++u) suf += ssum[u];
            unsigned cum = suf;
            for (int j = chunk - 1; j >= 0; --j) {
                const int g2 = t * chunk + j;
                const unsigned c = hist[g2];
                if (cum < r && cum + c >= r) { sfound[0] = (unsigned)g2; sfound[1] = cum; }
                cum += c;
            }
        }
        __syncthreads();
        const unsigned fd = sfound[0], ca = sfound[1];
        r -= ca;
        prefix |= fd << ((pass == 0) ? 21 : (pass == 1) ? 10 : 0);
        __syncthreads();
    }
    // prefix = T (key of the K-th largest); r = # of ties to take (asc index)
    const unsigned T = prefix;
    const float tv = xkey_inv(T);

    if (t == 0) tcnt = 0;
    __syncthreads();
    for (unsigned i = t; i < M; i += 1024) {
        const unsigned key = keys[i];
        if (key > T) {
            outb[idxs[i]] = 10.0f * xkey_inv(key);   // strictly above: selected
        } else if (key == T) {
            const unsigned p = atomicAdd(&tcnt, 1u);
            if (p < TIE_CAP) tlist[p] = i;
        }
    }
    __syncthreads();
    unsigned E = tcnt; if (E > TIE_CAP) E = TIE_CAP;
    for (unsigned j = t; j < E; j += 1024) {
        const unsigned idxj = idxs[tlist[j]];
        unsigned rank = 0;
        for (unsigned k2 = 0; k2 < E; ++k2) rank += (idxs[tlist[k2]] < idxj) ? 1u : 0u;
        if (rank < r) outb[idxj] = 10.0f * tv;
    }
}

extern "C" void kernel_launch(void* const* d_in, const int* in_sizes, int n_in,
                              void* d_out, int out_size, void* d_ws, size_t ws_size,
                              hipStream_t stream)
{
    const f32x4* x = (const f32x4*)d_in[0];
    char* wsb = (char*)d_ws;
    f32x4*    mean = (f32x4*)(wsb + OFF_MEAN);
    unsigned* hist = (unsigned*)(wsb + OFF_HIST);
    unsigned* ckey = (unsigned*)(wsb + OFF_CKEY);
    unsigned* cidx = (unsigned*)(wsb + OFF_CIDX);
    unsigned* ccnt = (unsigned*)(wsb + OFF_CCNT);
    unsigned* meta = (unsigned*)(wsb + OFF_META);

    zero_kernel<<<256, 256, 0, stream>>>(hist, ccnt);
    mean_hist_kernel<<<B * N4 / (256 * STREAMS), 256, 0, stream>>>(
        x, mean, hist, (f32x4*)d_out);
    select_bin_kernel<<<B, 256, 0, stream>>>(hist, meta);
    collect_kernel<<<B * N4 / 256, 256, 0, stream>>>(mean, meta, ckey, cidx, ccnt);
    radix_select_scatter_kernel<<<B, 1024, 0, stream>>>(ckey, cidx, ccnt, (float*)d_out);
}